// Round 14
// baseline (123.931 us; speedup 1.0000x reference)
//
#include <hip/hip_runtime.h>
#include <stdint.h>

#define DMAX 80
#define BLK  256
#define XW   96      // xsel row stride (>= m+1, sentinel 1.0 at k>=m)
#define EPB  4096    // output elements per block (16 KB)

typedef float f32x4 __attribute__((ext_vector_type(4)));

// ---------------------------------------------------------------------------
// Setup: mask detect + compact idx; coltab of 3-index entries i|j<<8|k<<16
// (column c = xsel[i]*xsel[j]*xsel[k], sentinel index m -> 1.0), plus 3
// shifted copies (copy s at coltab[s*tpad + (c-s)] holds column c) so any
// column phase s = c&3 has a 16B-aligned uint4 load.
//   [0,m)      order-1: (c, m, m)
//   [m, m+P)   order-2: (i, j, m)
//   [m+P, T)   order-3: (i, j, k), k in [j,m) per pair (i,j)
// ---------------------------------------------------------------------------
__global__ void maskde_setup(const void* __restrict__ mask_raw, int m,
                             int* __restrict__ idx_out,
                             uint32_t* __restrict__ coltab,
                             int tpad, int T, int P) {
    int tid = blockIdx.x * blockDim.x + threadIdx.x;

    if (tid == 0) {
        const uint8_t* b8  = (const uint8_t*)mask_raw;
        const int*     b32 = (const int*)mask_raw;
        const float*   bf  = (const float*)mask_raw;
        int cnt = 0; bool ok = true;
        for (int i = 0; i < DMAX; ++i) { uint8_t v = b8[i]; if (v > 1) ok = false; cnt += (v != 0); }
        int mode;
        if (ok && cnt == m) {
            mode = 0;
        } else {
            cnt = 0; ok = true;
            for (int i = 0; i < DMAX; ++i) { int v = b32[i]; if (v != 0 && v != 1) ok = false; cnt += (v != 0); }
            mode = (ok && cnt == m) ? 1 : 2;
        }
        int k = 0;
        for (int i = 0; i < DMAX && k < m; ++i) {
            bool on = (mode == 0) ? (b8[i] != 0)
                    : (mode == 1) ? (b32[i] != 0)
                                  : (bf[i] != 0.0f);
            if (on) idx_out[k++] = i;
        }
    }

    int stride = gridDim.x * blockDim.x;
    for (int p = tid; p < P; p += stride) {
        int rem = p, i = 0;
        while (rem >= m - i) { rem -= (m - i); ++i; }
        int j = i + rem;

        #define WR4(c, v) do {                                              \
            int _c = (c); uint32_t _v = (v);                                \
            coltab[_c] = _v;                                                \
            if (_c >= 1) coltab[tpad     + _c - 1] = _v;                    \
            if (_c >= 2) coltab[2 * tpad + _c - 2] = _v;                    \
            if (_c >= 3) coltab[3 * tpad + _c - 3] = _v;                    \
        } while (0)

        uint32_t mm8  = (uint32_t)m << 8;
        uint32_t mm16 = (uint32_t)m << 16;
        if (p < m)
            WR4(p, (uint32_t)p | mm8 | mm16);                       // order-1
        WR4(m + p, (uint32_t)i | ((uint32_t)j << 8) | mm16);        // order-2

        int mi = m - i;
        long long Si  = ((long long)m * (m + 1) * (m + 2)
                       - (long long)mi * (mi + 1) * (mi + 2)) / 6;
        int Rij = ((m - i) + (m - j + 1)) * (j - i) / 2;
        int base = m + P + (int)Si + Rij;
        uint32_t ij = (uint32_t)i | ((uint32_t)j << 8);
        for (int k3 = j; k3 < m; ++k3)
            WR4(base + (k3 - j), ij | ((uint32_t)k3 << 16));
        #undef WR4
    }
}

// ---------------------------------------------------------------------------
// xsel[row*XW + k] = x[row*80 + idx[k]] for k<m, 1.0 for k>=m (sentinel).
// ---------------------------------------------------------------------------
__global__ void maskde_xsel(const float* __restrict__ x,
                            const int* __restrict__ idx,
                            float* __restrict__ xsel, int m, int rows) {
    int g = blockIdx.x * BLK + threadIdx.x;
    int total = rows * XW;
    for (; g < total; g += gridDim.x * BLK) {
        int row = g / XW, k = g - row * XW;
        xsel[g] = (k < m) ? x[row * DMAX + idx[k]] : 1.0f;
    }
}

// ---------------------------------------------------------------------------
// Expand, fill-shaped, prologue-free: block b writes flat [b*EPB,(b+1)*EPB)
// (consecutive blocks = consecutive bytes).  Prologue = 2x96-float xls
// gather + ONE barrier (no pps build).  Hot loop: 1 aligned uint4 table
// load (L2) + 12 LDS reads + 8 muls + 1 aligned float4 store, 4 iterations
// per thread.
// ---------------------------------------------------------------------------
__global__ __launch_bounds__(BLK) void
maskde_expand(const float* __restrict__ xsel,
              const uint32_t* __restrict__ coltab, int tpad,
              float* __restrict__ out, int T, int rows, int total) {
    __shared__ float xls0[XW];
    __shared__ float xls1[XW];

    const int tid  = threadIdx.x;
    const int e0   = blockIdx.x * EPB;
    if (e0 >= total) return;
    const int eend = (e0 + EPB < total) ? e0 + EPB : total;
    const int r0   = e0 / T;
    const int r0start = r0 * T;
    const bool need1 = ((eend - 1) / T) > r0;   // span crosses into row r0+1

    // prologue: gather selected values (lazy for second row)
    if (tid < XW) {
        xls0[tid] = xsel[r0 * XW + tid];
    } else if (tid >= 128 && tid < 128 + XW) {
        int k = tid - 128;
        xls1[k] = need1 ? xsel[(r0 + 1) * XW + k] : 1.0f;
    }
    __syncthreads();

#pragma unroll
    for (int it = 0; it < EPB / (4 * BLK); ++it) {
        int ee = e0 + (tid << 2) + it * (4 * BLK);
        if (ee >= total) break;
        int c = ee - r0start;
        const float* xS = xls0;
        if (c >= T) { c -= T; xS = xls1; }

        if (c <= T - 4 && ee + 3 < total) {
            int s = c & 3;
            uint4 t = *(const uint4*)(coltab + (size_t)s * tpad + (c - s));
            f32x4 o;
            o.x = xS[t.x & 0xFF] * xS[(t.x >> 8) & 0xFF] * xS[t.x >> 16];
            o.y = xS[t.y & 0xFF] * xS[(t.y >> 8) & 0xFF] * xS[t.y >> 16];
            o.z = xS[t.z & 0xFF] * xS[(t.z >> 8) & 0xFF] * xS[t.z >> 16];
            o.w = xS[t.w & 0xFF] * xS[(t.w >> 8) & 0xFF] * xS[t.w >> 16];
            *(f32x4*)(out + ee) = o;   // ee % 4 == 0 -> 16B aligned
        } else {
            // row-crossing quad or buffer tail: scalar (base table copy)
            for (int u = 0; u < 4; ++u) {
                int e2 = ee + u;
                if (e2 >= total) break;
                int c2 = e2 - r0start;
                const float* x2 = xls0;
                if (c2 >= T) { c2 -= T; x2 = xls1; }
                uint32_t en = coltab[c2];
                out[e2] = x2[en & 0xFF] * x2[(en >> 8) & 0xFF] * x2[en >> 16];
            }
        }
    }
}

extern "C" void kernel_launch(void* const* d_in, const int* in_sizes, int n_in,
                              void* d_out, int out_size, void* d_ws, size_t ws_size,
                              hipStream_t stream) {
    const float* x    = (const float*)d_in[0];
    const void*  mask = d_in[1];
    float*       out  = (float*)d_out;

    int rows = in_sizes[0] / DMAX;
    if (rows <= 0 || out_size <= 0) return;
    long long Tll = (long long)out_size / rows;

    // recover m from T(m) = m + m(m+1)/2 + m(m+1)(m+2)/6
    int m = -1;
    for (int mm = 0; mm <= DMAX; ++mm) {
        long long t = (long long)mm
                    + (long long)mm * (mm + 1) / 2
                    + (long long)mm * (mm + 1) * (mm + 2) / 6;
        if (t == Tll) { m = mm; break; }
    }
    if (m <= 0) return;

    int T     = (int)Tll;
    int P     = m * (m + 1) / 2;
    int tpad  = (T + 3) & ~3;
    int total = rows * T;

    // workspace layout (256B-aligned regions)
    char* ws = (char*)d_ws;
    int*      idx    = (int*)ws;                              // 512 B
    uint32_t* coltab = (uint32_t*)(ws + 32768);               // 4*tpad u32
    size_t off_xsel  = 32768 + (size_t)4 * tpad * 4 + 256;
    off_xsel = (off_xsel + 255) & ~(size_t)255;
    float*    xsel   = (float*)(ws + off_xsel);               // rows*XW f32

    int sblocks = (P + 255) / 256;
    if (sblocks < 1) sblocks = 1;
    maskde_setup<<<sblocks, 256, 0, stream>>>(mask, m, idx, coltab,
                                              tpad, T, P);

    int xblocks = (rows * XW + BLK - 1) / BLK;
    if (xblocks > 2048) xblocks = 2048;
    maskde_xsel<<<xblocks, BLK, 0, stream>>>(x, idx, xsel, m, rows);

    int nb = (total + EPB - 1) / EPB;
    maskde_expand<<<nb, BLK, 0, stream>>>(xsel, coltab, tpad,
                                          out, T, rows, total);
}